// Round 1
// baseline (373.769 us; speedup 1.0000x reference)
//
#include <hip/hip_runtime.h>

#define DIN 256

typedef __attribute__((ext_vector_type(8))) short short8;
typedef __attribute__((ext_vector_type(4))) float f32x4;
typedef __attribute__((ext_vector_type(4))) unsigned short u16x4;

// ws layout (bytes)
#define OFF_W1T 0          // [256][256] bf16  (transposed, BN-folded)
#define OFF_W2T 131072     // [256][128] bf16
#define OFF_A4T 196608     // [128][128] bf16  (att_w[4])
#define OFF_OWT 229376     // [64][128]  bf16
#define OFF_B1  245760     // [256] f32
#define OFF_B2  246784     // [256] f32
#define OFF_B3  247808     // [128] f32
#define OFF_B4  248320     // [64]  f32
// total 248576 bytes of d_ws used

__device__ __forceinline__ unsigned short f2bf(float f){
  unsigned u = __builtin_bit_cast(unsigned, f);
  return (unsigned short)((u + 0x7fffu + ((u >> 16) & 1u)) >> 16);  // RNE
}

__device__ __forceinline__ short8 cvt8(float4 a, float4 b){
  short8 r;
  r[0] = (short)f2bf(a.x); r[1] = (short)f2bf(a.y);
  r[2] = (short)f2bf(a.z); r[3] = (short)f2bf(a.w);
  r[4] = (short)f2bf(b.x); r[5] = (short)f2bf(b.y);
  r[6] = (short)f2bf(b.z); r[7] = (short)f2bf(b.w);
  return r;
}

// ---------------- prep: fold BN into weights, transpose to [col][k], cast bf16 ----------------
__global__ void tabnet_prep(
    const float* __restrict__ w1, const float* __restrict__ b1, const float* __restrict__ g1, const float* __restrict__ be1,
    const float* __restrict__ w2, const float* __restrict__ b2, const float* __restrict__ g2, const float* __restrict__ be2,
    const float* __restrict__ aw, const float* __restrict__ ab, const float* __restrict__ ag, const float* __restrict__ abe,
    const float* __restrict__ ow, const float* __restrict__ ob, unsigned char* __restrict__ ws)
{
  const float inv = 1.0f / sqrtf(1.0f + 1e-3f);   // keras BN eps=1e-3, mean=0 var=1
  unsigned short* W1T = (unsigned short*)(ws + OFF_W1T);
  unsigned short* W2T = (unsigned short*)(ws + OFF_W2T);
  unsigned short* A4T = (unsigned short*)(ws + OFF_A4T);
  unsigned short* OWT = (unsigned short*)(ws + OFF_OWT);
  float* B1 = (float*)(ws + OFF_B1);
  float* B2 = (float*)(ws + OFF_B2);
  float* B3 = (float*)(ws + OFF_B3);
  float* B4 = (float*)(ws + OFF_B4);

  int tid = blockIdx.x * blockDim.x + threadIdx.x;
  int np  = gridDim.x * blockDim.x;
  for (int i = tid; i < 256*256; i += np){ int c = i >> 8, k = i & 255; W1T[c*256+k] = f2bf(w1[k*256+c] * (g1[c]*inv)); }
  for (int i = tid; i < 256*128; i += np){ int c = i >> 7, k = i & 127; W2T[c*128+k] = f2bf(w2[k*256+c] * (g2[c]*inv)); }
  for (int i = tid; i < 128*128; i += np){ int c = i >> 7, k = i & 127; A4T[c*128+k] = f2bf(aw[4*128*128 + k*128+c] * (ag[4*128+c]*inv)); }
  for (int i = tid; i < 64*128;  i += np){ int c = i >> 7, k = i & 127; OWT[c*128+k] = f2bf(ow[k*64+c]); }
  for (int i = tid; i < 256; i += np){ B1[i] = b1[i]*(g1[i]*inv) + be1[i]; B2[i] = b2[i]*(g2[i]*inv) + be2[i]; }
  for (int i = tid; i < 128; i += np){ B3[i] = ab[4*128+i]*(ag[4*128+i]*inv) + abe[4*128+i]; }
  for (int i = tid; i < 64;  i += np){ B4[i] = ob[i]; }
}

// ---------------- fused main kernel ----------------
// weight staging: LDS layout per k-block is [C cols][32 k] bf16 packed (64B/col).
template<int C, int K>
__device__ __forceinline__ void load_w_regs(const unsigned char* __restrict__ wsrc, int kb, uint4* r){
  const int tid = threadIdx.x;
  #pragma unroll
  for (int i = 0; i < C/64; ++i){
    const int f   = tid*(C/4) + i*16;     // flat byte offset in the k-block image
    const int col = f >> 6;
    const int wi  = f & 63;
    r[i] = *(const uint4*)(wsrc + (size_t)col*(2*K) + (size_t)kb*64 + wi);
  }
}
template<int C>
__device__ __forceinline__ void write_w_lds(unsigned char* dst, const uint4* r){
  const int tid = threadIdx.x;
  #pragma unroll
  for (int i = 0; i < C/64; ++i)
    *(uint4*)(dst + tid*(C/4) + i*16) = r[i];
}

template<int NT>
__device__ __forceinline__ void mfma_nt(const unsigned char* buf, short8 af, f32x4* acc, int lr, int lq){
  #pragma unroll
  for (int t = 0; t < NT; ++t){
    short8 bfr = *(const short8*)(buf + ((t*16 + lr) << 6) + (lq << 4));
    acc[t] = __builtin_amdgcn_mfma_f32_16x16x32_bf16(af, bfr, acc[t], 0, 0, 0);
  }
}

// A-fragment from the per-wave transpose buffer ([col][16 rows] bf16)
__device__ __forceinline__ short8 afrag_tt(const unsigned short* mytt, int kb, int lr, int lq){
  short8 r;
  #pragma unroll
  for (int j = 0; j < 8; ++j)
    r[j] = (short)mytt[(kb*32 + lq*8 + j)*16 + lr];
  return r;
}

#define STAGE_SYNC() do { \
    asm volatile("s_waitcnt lgkmcnt(0)" ::: "memory"); \
    __builtin_amdgcn_s_barrier(); \
    __builtin_amdgcn_sched_barrier(0); \
  } while (0)

__global__ void __launch_bounds__(256) tabnet_main(
    const float* __restrict__ X, const unsigned char* __restrict__ ws, float* __restrict__ out)
{
  __shared__ __align__(16) unsigned char wbuf[2][16384];
  __shared__ __align__(16) unsigned short ttbuf[4][2048];   // per-wave [128 col][16 row] bf16

  const int tid = threadIdx.x;
  const int w   = tid >> 6;
  const int l   = tid & 63;
  const int lr  = l & 15;
  const int lq  = l >> 4;
  const long rowbase = (long)blockIdx.x * 64 + w * 16;
  unsigned short* mytt = ttbuf[w];

  const float* B1 = (const float*)(ws + OFF_B1);
  const float* B2 = (const float*)(ws + OFF_B2);
  const float* B3 = (const float*)(ws + OFF_B3);
  const float* B4 = (const float*)(ws + OFF_B4);

  int cur = 0;

  // ============ stage 1: X(64x256) @ W1(256x256) -> bias -> GLU -> T1(64x128) ============
  f32x4 acc1[16];
  #pragma unroll
  for (int t = 0; t < 16; ++t) acc1[t] = (f32x4){0.f,0.f,0.f,0.f};
  {
    uint4 r0[4];
    load_w_regs<256,256>(ws + OFF_W1T, 0, r0);
    write_w_lds<256>(wbuf[cur], r0);
    for (int kb = 0; kb < 8; ++kb){
      uint4 rn[4];
      if (kb < 7) load_w_regs<256,256>(ws + OFF_W1T, kb+1, rn);
      STAGE_SYNC();
      const float* xp = X + (rowbase + lr) * DIN + kb*32 + lq*8;
      float4 xa = *(const float4*)xp;
      float4 xb = *(const float4*)(xp + 4);
      short8 af = cvt8(xa, xb);
      mfma_nt<16>(wbuf[cur], af, acc1, lr, lq);
      if (kb < 7) write_w_lds<256>(wbuf[cur^1], rn);
      cur ^= 1;
    }
  }
  #pragma unroll
  for (int t = 0; t < 8; ++t){
    float biasA = B1[t*16 + lr];
    float biasB = B1[t*16 + lr + 128];
    u16x4 pv;
    #pragma unroll
    for (int r = 0; r < 4; ++r){
      float ha = acc1[t][r]   + biasA;
      float hb = acc1[t+8][r] + biasB;
      pv[r] = f2bf(ha * (1.f / (1.f + __expf(-hb))));
    }
    *(u16x4*)(mytt + (t*16 + lr)*16 + lq*4) = pv;
  }

  // ============ stage 2: T1(64x128) @ W2(128x256) -> bias -> GLU -> T(64x128) ============
  f32x4 acc2[16];
  #pragma unroll
  for (int t = 0; t < 16; ++t) acc2[t] = (f32x4){0.f,0.f,0.f,0.f};
  {
    uint4 r0[4];
    load_w_regs<256,128>(ws + OFF_W2T, 0, r0);
    write_w_lds<256>(wbuf[cur], r0);
    for (int kb = 0; kb < 4; ++kb){
      uint4 rn[4];
      if (kb < 3) load_w_regs<256,128>(ws + OFF_W2T, kb+1, rn);
      STAGE_SYNC();
      short8 af = afrag_tt(mytt, kb, lr, lq);
      mfma_nt<16>(wbuf[cur], af, acc2, lr, lq);
      if (kb < 3) write_w_lds<256>(wbuf[cur^1], rn);
      cur ^= 1;
    }
  }
  f32x4 tk[8];   // keep T in f32 regs for stage 4
  #pragma unroll
  for (int t = 0; t < 8; ++t){
    float biasA = B2[t*16 + lr];
    float biasB = B2[t*16 + lr + 128];
    u16x4 pv;
    #pragma unroll
    for (int r = 0; r < 4; ++r){
      float ha = acc2[t][r]   + biasA;
      float hb = acc2[t+8][r] + biasB;
      float v  = ha * (1.f / (1.f + __expf(-hb)));
      tk[t][r] = v;
      pv[r] = f2bf(v);
    }
    *(u16x4*)(mytt + (t*16 + lr)*16 + lq*4) = pv;
  }

  // ============ stage 3: T @ att_w4(128x128) -> bias -> z ============
  f32x4 acc3[8];
  #pragma unroll
  for (int t = 0; t < 8; ++t) acc3[t] = (f32x4){0.f,0.f,0.f,0.f};
  {
    uint4 r0[2];
    load_w_regs<128,128>(ws + OFF_A4T, 0, r0);
    write_w_lds<128>(wbuf[cur], r0);
    for (int kb = 0; kb < 4; ++kb){
      uint4 rn[2];
      if (kb < 3) load_w_regs<128,128>(ws + OFF_A4T, kb+1, rn);
      STAGE_SYNC();
      short8 af = afrag_tt(mytt, kb, lr, lq);
      mfma_nt<8>(wbuf[cur], af, acc3, lr, lq);
      if (kb < 3) write_w_lds<128>(wbuf[cur^1], rn);
      cur ^= 1;
    }
  }
  f32x4 z[8];
  #pragma unroll
  for (int t = 0; t < 8; ++t){
    float b3 = B3[t*16 + lr];
    #pragma unroll
    for (int r = 0; r < 4; ++r) z[t][r] = acc3[t][r] + b3;
  }

  // ============ sparsemax per row (Michelot fixpoint; rows live in 16-lane quarters) ============
  float tau[4]; int cnt[4];
  #pragma unroll
  for (int r = 0; r < 4; ++r){
    float s = 0.f;
    #pragma unroll
    for (int t = 0; t < 8; ++t) s += z[t][r];
    #pragma unroll
    for (int m = 1; m <= 8; m <<= 1) s += __shfl_xor(s, m, 64);
    tau[r] = (s - 1.f) * (1.f/128.f);
    cnt[r] = 128;
  }
  for (int it = 0; it < 32; ++it){
    int ch = 0;
    #pragma unroll
    for (int r = 0; r < 4; ++r){
      float s2 = 0.f; int c2 = 0;
      #pragma unroll
      for (int t = 0; t < 8; ++t){
        float zz = z[t][r];
        if (zz > tau[r]) { s2 += zz; c2 += 1; }
      }
      #pragma unroll
      for (int m = 1; m <= 8; m <<= 1){ s2 += __shfl_xor(s2, m, 64); c2 += __shfl_xor(c2, m, 64); }
      tau[r] = (s2 - 1.f) / (float)c2;
      ch |= (c2 != cnt[r]);
      cnt[r] = c2;
    }
    if (!__any(ch)) break;
  }
  // P = T * mask -> transpose buffer for stage 4
  #pragma unroll
  for (int t = 0; t < 8; ++t){
    u16x4 pv;
    #pragma unroll
    for (int r = 0; r < 4; ++r){
      float m = z[t][r] - tau[r];
      m = m > 0.f ? m : 0.f;
      pv[r] = f2bf(tk[t][r] * m);
    }
    *(u16x4*)(mytt + (t*16 + lr)*16 + lq*4) = pv;
  }

  // ============ stage 4: P(64x128) @ out_w(128x64) + b -> out ============
  f32x4 acc4[4];
  #pragma unroll
  for (int t = 0; t < 4; ++t) acc4[t] = (f32x4){0.f,0.f,0.f,0.f};
  {
    uint4 r0[1];
    load_w_regs<64,128>(ws + OFF_OWT, 0, r0);
    write_w_lds<64>(wbuf[cur], r0);
    for (int kb = 0; kb < 4; ++kb){
      uint4 rn[1];
      if (kb < 3) load_w_regs<64,128>(ws + OFF_OWT, kb+1, rn);
      STAGE_SYNC();
      short8 af = afrag_tt(mytt, kb, lr, lq);
      mfma_nt<4>(wbuf[cur], af, acc4, lr, lq);
      if (kb < 3) write_w_lds<64>(wbuf[cur^1], rn);
      cur ^= 1;
    }
  }
  #pragma unroll
  for (int t = 0; t < 4; ++t){
    float b4 = B4[t*16 + lr];
    #pragma unroll
    for (int r = 0; r < 4; ++r)
      out[(rowbase + lq*4 + r)*64 + t*16 + lr] = acc4[t][r] + b4;
  }
}

extern "C" void kernel_launch(void* const* d_in, const int* in_sizes, int n_in,
                              void* d_out, int out_size, void* d_ws, size_t ws_size,
                              hipStream_t stream)
{
  const float* feat = (const float*)d_in[0];
  const float* w1  = (const float*)d_in[1];
  const float* b1  = (const float*)d_in[2];
  const float* g1  = (const float*)d_in[3];
  const float* be1 = (const float*)d_in[4];
  const float* w2  = (const float*)d_in[5];
  const float* b2  = (const float*)d_in[6];
  const float* g2  = (const float*)d_in[7];
  const float* be2 = (const float*)d_in[8];
  const float* aw  = (const float*)d_in[9];
  const float* ab  = (const float*)d_in[10];
  const float* ag  = (const float*)d_in[11];
  const float* abe = (const float*)d_in[12];
  const float* ow  = (const float*)d_in[13];
  const float* ob  = (const float*)d_in[14];
  unsigned char* ws = (unsigned char*)d_ws;

  tabnet_prep<<<128, 256, 0, stream>>>(w1,b1,g1,be1, w2,b2,g2,be2, aw,ab,ag,abe, ow,ob, ws);
  tabnet_main<<<4096, 256, 0, stream>>>(feat, ws, (float*)d_out);
}

// Round 2
// 198.807 us; speedup vs baseline: 1.8801x; 1.8801x over previous
//
#include <hip/hip_runtime.h>

typedef __attribute__((ext_vector_type(8))) short short8;
typedef __attribute__((ext_vector_type(4))) float f32x4;

// ws layout (bytes): weight images pre-arranged per 32-k block, [col][32k] bf16
#define OFF_W1 0          // 8 images x 16384 B
#define OFF_W2 131072     // 4 images x 16384 B
#define OFF_A4 196608     // 4 images x 8192 B
#define OFF_OW 229376     // 4 images x 4096 B
#define OFF_B1 245760     // 256 f32
#define OFF_B2 246784     // 256 f32
#define OFF_B3 247808     // 128 f32
#define OFF_B4 248320     // 64 f32

__device__ __forceinline__ unsigned short f2bf(float f){
  unsigned u = __builtin_bit_cast(unsigned, f);
  return (unsigned short)((u + 0x7fffu + ((u >> 16) & 1u)) >> 16);  // RNE
}

__device__ __forceinline__ short8 cvt8(float4 a, float4 b){
  short8 r;
  r[0] = (short)f2bf(a.x); r[1] = (short)f2bf(a.y);
  r[2] = (short)f2bf(a.z); r[3] = (short)f2bf(a.w);
  r[4] = (short)f2bf(b.x); r[5] = (short)f2bf(b.y);
  r[6] = (short)f2bf(b.z); r[7] = (short)f2bf(b.w);
  return r;
}

// ---------------- prep: fold BN, rearrange to per-kb images [col][32k] bf16 ----------------
__global__ void tabnet_prep(
    const float* __restrict__ w1, const float* __restrict__ b1, const float* __restrict__ g1, const float* __restrict__ be1,
    const float* __restrict__ w2, const float* __restrict__ b2, const float* __restrict__ g2, const float* __restrict__ be2,
    const float* __restrict__ aw, const float* __restrict__ ab, const float* __restrict__ ag, const float* __restrict__ abe,
    const float* __restrict__ ow, const float* __restrict__ ob, unsigned char* __restrict__ ws)
{
  const float inv = 1.0f / sqrtf(1.0f + 1e-3f);
  unsigned short* W1R = (unsigned short*)(ws + OFF_W1);
  unsigned short* W2R = (unsigned short*)(ws + OFF_W2);
  unsigned short* A4R = (unsigned short*)(ws + OFF_A4);
  unsigned short* OWR = (unsigned short*)(ws + OFF_OW);
  float* B1 = (float*)(ws + OFF_B1);
  float* B2 = (float*)(ws + OFF_B2);
  float* B3 = (float*)(ws + OFF_B3);
  float* B4 = (float*)(ws + OFF_B4);

  int tid = blockIdx.x * blockDim.x + threadIdx.x;
  int np  = gridDim.x * blockDim.x;
  for (int i = tid; i < 256*256; i += np){
    int c = i >> 8, k = i & 255;
    W1R[(k>>5)*8192 + c*32 + (k&31)] = f2bf(w1[k*256+c] * (g1[c]*inv));
  }
  for (int i = tid; i < 256*128; i += np){
    int c = i >> 7, k = i & 127;
    W2R[(k>>5)*8192 + c*32 + (k&31)] = f2bf(w2[k*256+c] * (g2[c]*inv));
  }
  for (int i = tid; i < 128*128; i += np){
    int c = i >> 7, k = i & 127;
    A4R[(k>>5)*4096 + c*32 + (k&31)] = f2bf(aw[4*128*128 + k*128+c] * (ag[4*128+c]*inv));
  }
  for (int i = tid; i < 64*128; i += np){
    int c = i & 63, k = i >> 6;
    OWR[(k>>5)*2048 + c*32 + (k&31)] = f2bf(ow[k*64+c]);
  }
  for (int i = tid; i < 256; i += np){ B1[i] = b1[i]*(g1[i]*inv) + be1[i]; B2[i] = b2[i]*(g2[i]*inv) + be2[i]; }
  for (int i = tid; i < 128; i += np){ B3[i] = ab[4*128+i]*(ag[4*128+i]*inv) + abe[4*128+i]; }
  for (int i = tid; i < 64;  i += np){ B4[i] = ob[i]; }
}

// ---------------- fused main kernel ----------------
#define FENCE() __builtin_amdgcn_sched_barrier(0)
template<int N> __device__ __forceinline__ void waitv(){
  asm volatile("s_waitcnt vmcnt(%0)" :: "i"(N) : "memory");
}
__device__ __forceinline__ void barx(){
  FENCE(); __builtin_amdgcn_s_barrier(); FENCE();
}

__device__ __forceinline__ void gl_lds16(const void* g, void* l){
  __builtin_amdgcn_global_load_lds(
      (const __attribute__((address_space(1))) unsigned int*)g,
      (__attribute__((address_space(3))) unsigned int*)l, 16, 0, 0);
}

// stage R rounds of 4KB each: wave w covers lds [j*4096 + w*1024, +1024)
template<int R>
__device__ __forceinline__ void stage_glds(const unsigned char* img, unsigned char* lds, int w, int l){
  #pragma unroll
  for (int j = 0; j < R; ++j)
    gl_lds16(img + j*4096 + w*1024 + l*16, lds + j*4096 + w*1024);
}

template<int NT>
__device__ __forceinline__ void mfma_dual(const unsigned char* buf, short8 a0, short8 a1,
                                          f32x4* acc0, f32x4* acc1, int lr, int lq){
  #pragma unroll
  for (int t = 0; t < NT; ++t){
    short8 b = *(const short8*)(buf + ((t*16 + lr) << 6) + (lq << 4));
    acc0[t] = __builtin_amdgcn_mfma_f32_16x16x32_bf16(a0, b, acc0[t], 0, 0, 0);
    acc1[t] = __builtin_amdgcn_mfma_f32_16x16x32_bf16(a1, b, acc1[t], 0, 0, 0);
  }
}

// tt: [16 rows][256B] per tile, byte within row = (2*col) ^ ((row&7)<<4)
__device__ __forceinline__ short8 afrag(const unsigned char* ttb, int kb, int lr, int lq){
  int off = (lr << 8) + (((kb << 6) + (lq << 4)) ^ ((lr & 7) << 4));
  return *(const short8*)(ttb + off);
}
__device__ __forceinline__ void tt_write(unsigned char* ttb, int row, int col, unsigned short v){
  *(unsigned short*)(ttb + (row << 8) + ((col*2) ^ ((row & 7) << 4))) = v;
}

__global__ void __launch_bounds__(256, 2) tabnet_main(
    const float* __restrict__ X, const unsigned char* __restrict__ ws, float* __restrict__ out)
{
  __shared__ __align__(16) unsigned char wb[2][16384];
  __shared__ __align__(16) unsigned char tt[4][2][4096];

  const int tid = threadIdx.x;
  const int w  = tid >> 6;
  const int l  = tid & 63;
  const int lr = l & 15;
  const int lq = l >> 4;
  const long rowbase = (long)blockIdx.x * 128 + w * 32;
  unsigned char* tt0 = tt[w][0];
  unsigned char* tt1 = tt[w][1];

  const float* B1 = (const float*)(ws + OFF_B1);
  const float* B2 = (const float*)(ws + OFF_B2);
  const float* B3 = (const float*)(ws + OFF_B3);
  const float* B4 = (const float*)(ws + OFF_B4);

  const float* xbase = X + (rowbase + lr) * 256 + lq * 8;

  // ================= stage 1: X(128x256) @ W1 -> GLU -> T1 =================
  f32x4 acc1v[2][16];
  #pragma unroll
  for (int t = 0; t < 16; ++t){ acc1v[0][t] = (f32x4){0,0,0,0}; acc1v[1][t] = (f32x4){0,0,0,0}; }

  float4 xr[2][4];
  #define LDX(kb, dst) do { \
      const float* p_ = xbase + (kb)*32; \
      dst[0] = *(const float4*)p_;          dst[1] = *(const float4*)(p_ + 4); \
      dst[2] = *(const float4*)(p_ + 4096); dst[3] = *(const float4*)(p_ + 4100); \
    } while (0)

  LDX(0, xr[0]);
  stage_glds<4>(ws + OFF_W1,         wb[0], w, l);
  LDX(1, xr[1]);
  stage_glds<4>(ws + OFF_W1 + 16384, wb[1], w, l);

  #pragma unroll
  for (int kb = 0; kb < 8; ++kb){
    if (kb < 7) waitv<8>(); else waitv<4>();
    barx();
    short8 a0 = cvt8(xr[kb&1][0], xr[kb&1][1]);
    short8 a1 = cvt8(xr[kb&1][2], xr[kb&1][3]);
    mfma_dual<16>(wb[kb&1], a0, a1, acc1v[0], acc1v[1], lr, lq);
    if (kb < 6) LDX(kb+2, xr[kb&1]);
    barx();
    if (kb < 6) stage_glds<4>(ws + OFF_W1 + (kb+2)*16384, wb[kb&1], w, l);
    else        stage_glds<4>(ws + OFF_W2 + (kb-6)*16384, wb[kb&1], w, l);
  }

  // epilogue 1: GLU -> tt (bf16)
  #pragma unroll
  for (int t = 0; t < 8; ++t){
    float ba = B1[t*16 + lr], bb = B1[128 + t*16 + lr];
    #pragma unroll
    for (int tl = 0; tl < 2; ++tl){
      unsigned char* td = tl ? tt1 : tt0;
      #pragma unroll
      for (int r = 0; r < 4; ++r){
        float a = acc1v[tl][t][r]   + ba;
        float b = acc1v[tl][t+8][r] + bb;
        float v = a * (1.f / (1.f + __expf(-b)));
        tt_write(td, lq*4 + r, t*16 + lr, f2bf(v));
      }
    }
  }

  // ================= stage 2: T1 @ W2 -> GLU -> T =================
  f32x4 acc2v[2][16];
  #pragma unroll
  for (int t = 0; t < 16; ++t){ acc2v[0][t] = (f32x4){0,0,0,0}; acc2v[1][t] = (f32x4){0,0,0,0}; }

  #pragma unroll
  for (int kb = 0; kb < 4; ++kb){
    if (kb < 3) waitv<4>(); else waitv<2>();
    barx();
    short8 a0 = afrag(tt0, kb, lr, lq);
    short8 a1 = afrag(tt1, kb, lr, lq);
    mfma_dual<16>(wb[kb&1], a0, a1, acc2v[0], acc2v[1], lr, lq);
    barx();
    if (kb < 2) stage_glds<4>(ws + OFF_W2 + (kb+2)*16384, wb[kb&1], w, l);
    else        stage_glds<2>(ws + OFF_A4 + (kb-2)*8192,  wb[kb&1], w, l);
  }

  f32x4 tk[2][8];
  #pragma unroll
  for (int t = 0; t < 8; ++t){
    float ba = B2[t*16 + lr], bb = B2[128 + t*16 + lr];
    #pragma unroll
    for (int tl = 0; tl < 2; ++tl){
      unsigned char* td = tl ? tt1 : tt0;
      #pragma unroll
      for (int r = 0; r < 4; ++r){
        float a = acc2v[tl][t][r]   + ba;
        float b = acc2v[tl][t+8][r] + bb;
        float v = a * (1.f / (1.f + __expf(-b)));
        tk[tl][t][r] = v;
        tt_write(td, lq*4 + r, t*16 + lr, f2bf(v));
      }
    }
  }

  // ================= stage 3: T @ att_w4 -> z =================
  f32x4 acc3v[2][8];
  #pragma unroll
  for (int t = 0; t < 8; ++t){ acc3v[0][t] = (f32x4){0,0,0,0}; acc3v[1][t] = (f32x4){0,0,0,0}; }

  #pragma unroll
  for (int kb = 0; kb < 4; ++kb){
    if (kb < 3) waitv<2>(); else waitv<1>();
    barx();
    short8 a0 = afrag(tt0, kb, lr, lq);
    short8 a1 = afrag(tt1, kb, lr, lq);
    mfma_dual<8>(wb[kb&1], a0, a1, acc3v[0], acc3v[1], lr, lq);
    barx();
    if (kb < 2) stage_glds<2>(ws + OFF_A4 + (kb+2)*8192, wb[kb&1], w, l);
    else        stage_glds<1>(ws + OFF_OW + (kb-2)*4096, wb[kb&1], w, l);
  }

  // epilogue 3: z = acc3 + b3, sparsemax (Michelot fixpoint), P = T*mask -> tt
  f32x4 zv[2][8];
  #pragma unroll
  for (int t = 0; t < 8; ++t){
    float b3 = B3[t*16 + lr];
    #pragma unroll
    for (int tl = 0; tl < 2; ++tl){
      #pragma unroll
      for (int r = 0; r < 4; ++r) zv[tl][t][r] = acc3v[tl][t][r] + b3;
    }
  }

  float tau[2][4]; int cnt[2][4];
  #pragma unroll
  for (int tl = 0; tl < 2; ++tl){
    #pragma unroll
    for (int r = 0; r < 4; ++r){
      float s = 0.f;
      #pragma unroll
      for (int t = 0; t < 8; ++t) s += zv[tl][t][r];
      #pragma unroll
      for (int m = 1; m <= 8; m <<= 1) s += __shfl_xor(s, m, 64);
      tau[tl][r] = (s - 1.f) * (1.f/128.f);
      cnt[tl][r] = 128;
    }
  }
  for (int it = 0; it < 32; ++it){
    int ch = 0;
    #pragma unroll
    for (int tl = 0; tl < 2; ++tl){
      #pragma unroll
      for (int r = 0; r < 4; ++r){
        float s2 = 0.f; int c2 = 0;
        #pragma unroll
        for (int t = 0; t < 8; ++t){
          float zz = zv[tl][t][r];
          if (zz > tau[tl][r]) { s2 += zz; c2 += 1; }
        }
        #pragma unroll
        for (int m = 1; m <= 8; m <<= 1){ s2 += __shfl_xor(s2, m, 64); c2 += __shfl_xor(c2, m, 64); }
        tau[tl][r] = (s2 - 1.f) / (float)c2;
        ch |= (c2 != cnt[tl][r]);
        cnt[tl][r] = c2;
      }
    }
    if (!__any(ch)) break;
  }
  #pragma unroll
  for (int t = 0; t < 8; ++t){
    #pragma unroll
    for (int tl = 0; tl < 2; ++tl){
      unsigned char* td = tl ? tt1 : tt0;
      #pragma unroll
      for (int r = 0; r < 4; ++r){
        float m = zv[tl][t][r] - tau[tl][r];
        m = m > 0.f ? m : 0.f;
        tt_write(td, lq*4 + r, t*16 + lr, f2bf(tk[tl][t][r] * m));
      }
    }
  }

  // ================= stage 4: P @ out_w + b -> out =================
  f32x4 acc4v[2][4];
  #pragma unroll
  for (int t = 0; t < 4; ++t){ acc4v[0][t] = (f32x4){0,0,0,0}; acc4v[1][t] = (f32x4){0,0,0,0}; }

  #pragma unroll
  for (int kb = 0; kb < 4; ++kb){
    if (kb < 3) waitv<1>(); else waitv<0>();
    barx();
    short8 a0 = afrag(tt0, kb, lr, lq);
    short8 a1 = afrag(tt1, kb, lr, lq);
    mfma_dual<4>(wb[kb&1], a0, a1, acc4v[0], acc4v[1], lr, lq);
    barx();
    if (kb < 2) stage_glds<1>(ws + OFF_OW + (kb+2)*4096, wb[kb&1], w, l);
  }

  #pragma unroll
  for (int t = 0; t < 4; ++t){
    float b4 = B4[t*16 + lr];
    #pragma unroll
    for (int tl = 0; tl < 2; ++tl){
      #pragma unroll
      for (int r = 0; r < 4; ++r)
        out[(rowbase + tl*16 + lq*4 + r)*64 + t*16 + lr] = acc4v[tl][t][r] + b4;
    }
  }
}

extern "C" void kernel_launch(void* const* d_in, const int* in_sizes, int n_in,
                              void* d_out, int out_size, void* d_ws, size_t ws_size,
                              hipStream_t stream)
{
  const float* feat = (const float*)d_in[0];
  const float* w1  = (const float*)d_in[1];
  const float* b1  = (const float*)d_in[2];
  const float* g1  = (const float*)d_in[3];
  const float* be1 = (const float*)d_in[4];
  const float* w2  = (const float*)d_in[5];
  const float* b2  = (const float*)d_in[6];
  const float* g2  = (const float*)d_in[7];
  const float* be2 = (const float*)d_in[8];
  const float* aw  = (const float*)d_in[9];
  const float* ab  = (const float*)d_in[10];
  const float* ag  = (const float*)d_in[11];
  const float* abe = (const float*)d_in[12];
  const float* ow  = (const float*)d_in[13];
  const float* ob  = (const float*)d_in[14];
  unsigned char* ws = (unsigned char*)d_ws;

  tabnet_prep<<<128, 256, 0, stream>>>(w1,b1,g1,be1, w2,b2,g2,be2, aw,ab,ag,abe, ow,ob, ws);
  tabnet_main<<<2048, 256, 0, stream>>>(feat, ws, (float*)d_out);
}

// Round 3
// 143.825 us; speedup vs baseline: 2.5988x; 1.3823x over previous
//
#include <hip/hip_runtime.h>

typedef __attribute__((ext_vector_type(8)))  short short8;
typedef __attribute__((ext_vector_type(16))) float f32x16;

// ws layout (bytes)
#define OFF_S1 0          // 8 panels x 16384  ([64c][128k], cols = v(32)+g(32), k-half e)
#define OFF_S2 131072     // 4 panels x 16384  ([64c][128k])
#define OFF_S3 196608     // 4 panels x 8192   ([32c][128k])
#define OFF_S4 229376     // 2 panels x 8192   ([32c][128k])
#define OFF_B  245760     // 704 f32: B1[256] B2[256] B3[128] B4[64]

__device__ __forceinline__ unsigned short f2bf(float f){
  unsigned u = __builtin_bit_cast(unsigned, f);
  return (unsigned short)((u + 0x7fffu + ((u >> 16) & 1u)) >> 16);  // RNE
}
__device__ __forceinline__ float bf2f(short s){
  return __builtin_bit_cast(float, ((unsigned)(unsigned short)s) << 16);
}
__device__ __forceinline__ unsigned pk2(float lo, float hi){
  unsigned r;
  asm("v_cvt_pk_bf16_f32 %0, %1, %2" : "=v"(r) : "v"(lo), "v"(hi));
  return r;
}

// ---------------- prep: fold BN, build swizzled A-panels ----------------
// panel byte for col cc, k kl: cc*256 + ((kl*2) ^ ((cc&7)<<4))
__global__ void tabnet_prep(
    const float* __restrict__ w1, const float* __restrict__ b1, const float* __restrict__ g1, const float* __restrict__ be1,
    const float* __restrict__ w2, const float* __restrict__ b2, const float* __restrict__ g2, const float* __restrict__ be2,
    const float* __restrict__ aw, const float* __restrict__ ab, const float* __restrict__ ag, const float* __restrict__ abe,
    const float* __restrict__ ow, const float* __restrict__ ob, unsigned char* __restrict__ ws)
{
  const float inv = 1.0f / sqrtf(1.0f + 1e-3f);
  int tid = blockIdx.x * blockDim.x + threadIdx.x;
  int np  = gridDim.x * blockDim.x;

  // W1 [256k][256c] -> s1 panels (pair m, khalf e)
  for (int i = tid; i < 256*256; i += np){
    int k = i >> 8, c = i & 255;
    int m, cc;
    if (c < 128){ m = c >> 5; cc = c & 31; } else { m = (c-128) >> 5; cc = 32 + ((c-128) & 31); }
    int e = k >> 7, kl = k & 127;
    size_t byte = OFF_S1 + (size_t)(m*2+e)*16384 + cc*256 + (((kl<<1)) ^ ((cc&7)<<4));
    *(unsigned short*)(ws + byte) = f2bf(w1[k*256+c] * (g1[c]*inv));
  }
  // W2 [128k][256c] -> s2 panels
  for (int i = tid; i < 128*256; i += np){
    int k = i >> 8, c = i & 255;
    int m, cc;
    if (c < 128){ m = c >> 5; cc = c & 31; } else { m = (c-128) >> 5; cc = 32 + ((c-128) & 31); }
    size_t byte = OFF_S2 + (size_t)m*16384 + cc*256 + (((k<<1)) ^ ((cc&7)<<4));
    *(unsigned short*)(ws + byte) = f2bf(w2[k*256+c] * (g2[c]*inv));
  }
  // att_w[4] [128k][128c] -> s3 panels
  for (int i = tid; i < 128*128; i += np){
    int k = i >> 7, c = i & 127;
    int m = c >> 5, cc = c & 31;
    size_t byte = OFF_S3 + (size_t)m*8192 + cc*256 + (((k<<1)) ^ ((cc&7)<<4));
    *(unsigned short*)(ws + byte) = f2bf(aw[4*128*128 + k*128 + c] * (ag[4*128+c]*inv));
  }
  // out_w [128k][64c] -> s4 panels
  for (int i = tid; i < 128*64; i += np){
    int k = i >> 6, c = i & 63;
    int m = c >> 5, cc = c & 31;
    size_t byte = OFF_S4 + (size_t)m*8192 + cc*256 + (((k<<1)) ^ ((cc&7)<<4));
    *(unsigned short*)(ws + byte) = f2bf(ow[k*64 + c]);
  }
  float* B = (float*)(ws + OFF_B);
  for (int i = tid; i < 256; i += np){ B[i] = b1[i]*(g1[i]*inv) + be1[i]; B[256+i] = b2[i]*(g2[i]*inv) + be2[i]; }
  for (int i = tid; i < 128; i += np){ B[512+i] = ab[4*128+i]*(ag[4*128+i]*inv) + abe[4*128+i]; }
  for (int i = tid; i < 64;  i += np){ B[640+i] = ob[i]; }
}

// ---------------- main ----------------
#define FENCE() __builtin_amdgcn_sched_barrier(0)
template<int N> __device__ __forceinline__ void waitv(){
  asm volatile("s_waitcnt vmcnt(%0)" :: "i"(N) : "memory");
}
__device__ __forceinline__ void barx(){ FENCE(); __builtin_amdgcn_s_barrier(); FENCE(); }

__device__ __forceinline__ void gl_lds16(const void* g, void* l){
  __builtin_amdgcn_global_load_lds(
      (const __attribute__((address_space(1))) unsigned int*)g,
      (__attribute__((address_space(3))) unsigned int*)l, 16, 0, 0);
}

// stage a panel: R rounds of 4KB; wave w covers [w*1024, +1024) of each round
template<int R>
__device__ __forceinline__ void stage_panel(const unsigned char* src, unsigned char* lds, int w, int l){
  #pragma unroll
  for (int j = 0; j < R; ++j)
    gl_lds16(src + j*4096 + w*1024 + l*16, lds + j*4096 + w*1024);
}

__device__ __forceinline__ f32x16 zero16(){
  f32x16 z;
  #pragma unroll
  for (int i = 0; i < 16; ++i) z[i] = 0.f;
  return z;
}

__device__ __forceinline__ short8 afrag(const unsigned char* buf, int cc, int kb, int lh){
  int off = cc*256 + (((kb<<5) + (lh<<4)) ^ ((cc&7)<<4));
  return *(const short8*)(buf + off);
}

__device__ __forceinline__ unsigned sx32(unsigned v){ return (unsigned)__shfl_xor((int)v, 32, 64); }
__device__ __forceinline__ float    sx32f(float v){ return __shfl_xor(v, 32, 64); }

// build B-frags for kb = 2m, 2m+1 from 8 packed words (W[q] = bf16x2 of D-regs 2q,2q+1)
__device__ __forceinline__ void frags_from_words(const unsigned* W, int lh, short8* f0, short8* f1){
  #pragma unroll
  for (int kbl = 0; kbl < 2; ++kbl){
    const int g0 = kbl*2;
    unsigned own0 = lh ? W[2*(g0+1)]   : W[2*g0];
    unsigned own1 = lh ? W[2*(g0+1)+1] : W[2*g0+1];
    unsigned snd0 = lh ? W[2*g0]       : W[2*(g0+1)];
    unsigned snd1 = lh ? W[2*g0+1]     : W[2*(g0+1)+1];
    unsigned r0 = sx32(snd0), r1 = sx32(snd1);
    uint4 fw;
    fw.x = lh ? r0 : own0;   // j0,j1 (from lower half)
    fw.y = lh ? r1 : own1;   // j2,j3
    fw.z = lh ? own0 : r0;   // j4,j5 (from upper half)
    fw.w = lh ? own1 : r1;   // j6,j7
    short8 f = __builtin_bit_cast(short8, fw);
    if (kbl == 0) *f0 = f; else *f1 = f;
  }
}

__global__ void __launch_bounds__(256, 3) tabnet_main(
    const float* __restrict__ X, const unsigned char* __restrict__ ws, float* __restrict__ out)
{
  __shared__ __align__(16) unsigned char buf[2][16384];
  __shared__ __align__(16) float blds[704];

  const int tid = threadIdx.x;
  const int w   = tid >> 6;
  const int l   = tid & 63;
  const int lh  = l >> 5;      // lane half
  const int cc  = l & 31;      // col-lane / row-lane
  const long rowbase = (long)blockIdx.x * 128 + w * 32;

  // ---- prologue staging: P0, P1, biases ----
  stage_panel<4>(ws + OFF_S1,         buf[0], w, l);
  stage_panel<4>(ws + OFF_S1 + 16384, buf[1], w, l);
  if (w == 0){
    #pragma unroll
    for (int j = 0; j < 3; ++j)
      if (j*1024 + l*16 < 2816)
        gl_lds16(ws + OFF_B + j*1024 + l*16, (unsigned char*)blds + j*1024);
  }

  // ---- X load (32 rows x 256 k, one burst) + cvt to bf16 B-frags ----
  const float* xp = X + (rowbase + cc) * 256 + lh * 8;
  float4 xfa[16], xfb[16];
  #pragma unroll
  for (int K = 0; K < 16; ++K){
    xfa[K] = *(const float4*)(xp + K*16);
    xfb[K] = *(const float4*)(xp + K*16 + 4);
  }
  short8 xb[16];
  #pragma unroll
  for (int K = 0; K < 16; ++K){
    uint4 u;
    u.x = pk2(xfa[K].x, xfa[K].y); u.y = pk2(xfa[K].z, xfa[K].w);
    u.z = pk2(xfb[K].x, xfb[K].y); u.w = pk2(xfb[K].z, xfb[K].w);
    xb[K] = __builtin_bit_cast(short8, u);
  }
  barx();   // all waves: P0,P1,bias staged (vmcnt drained by cvt chain)

  // ================= stage 1: X @ W1 -> GLU -> T1-frags =================
  short8 t1b[8];
  #pragma unroll
  for (int m = 0; m < 4; ++m){
    f32x16 accv = zero16(), accg = zero16();
    #pragma unroll
    for (int e = 0; e < 2; ++e){
      const int p = m*2 + e;
      waitv<4>(); barx();
      const unsigned char* bp = buf[p & 1];
      #pragma unroll
      for (int kb = 0; kb < 8; ++kb){
        short8 av = afrag(bp, cc,      kb, lh);
        short8 ag = afrag(bp, cc + 32, kb, lh);
        const int K = e*8 + kb;
        accv = __builtin_amdgcn_mfma_f32_32x32x16_bf16(av, xb[K], accv, 0, 0, 0);
        accg = __builtin_amdgcn_mfma_f32_32x32x16_bf16(ag, xb[K], accg, 0, 0, 0);
      }
      barx();
      // stage P_{p+2}
      if (p+2 <= 7)       stage_panel<4>(ws + OFF_S1 + (p+2)*16384, buf[p & 1], w, l);
      else                stage_panel<4>(ws + OFF_S2 + (p-6)*16384, buf[p & 1], w, l);
    }
    // GLU epilogue -> packed words -> exchange -> frags kb 2m,2m+1
    unsigned W[8];
    #pragma unroll
    for (int q = 0; q < 4; ++q){
      float4 bv = *(const float4*)&blds[      m*32 + 8*q + 4*lh];
      float4 bg = *(const float4*)&blds[128 + m*32 + 8*q + 4*lh];
      float t0 = (accv[4*q+0] + bv.x) * (1.f/(1.f + __expf(-(accg[4*q+0] + bg.x))));
      float t1 = (accv[4*q+1] + bv.y) * (1.f/(1.f + __expf(-(accg[4*q+1] + bg.y))));
      float t2 = (accv[4*q+2] + bv.z) * (1.f/(1.f + __expf(-(accg[4*q+2] + bg.z))));
      float t3 = (accv[4*q+3] + bv.w) * (1.f/(1.f + __expf(-(accg[4*q+3] + bg.w))));
      W[2*q]   = pk2(t0, t1);
      W[2*q+1] = pk2(t2, t3);
    }
    frags_from_words(W, lh, &t1b[2*m], &t1b[2*m+1]);
  }

  // ================= stage 2: T1 @ W2 -> GLU -> T-frags =================
  short8 tb[8];
  #pragma unroll
  for (int m = 0; m < 4; ++m){
    const int p = 8 + m;
    f32x16 accv = zero16(), accg = zero16();
    if (p == 11) waitv<2>(); else waitv<4>();
    barx();
    const unsigned char* bp = buf[p & 1];
    #pragma unroll
    for (int kb = 0; kb < 8; ++kb){
      short8 av = afrag(bp, cc,      kb, lh);
      short8 ag = afrag(bp, cc + 32, kb, lh);
      accv = __builtin_amdgcn_mfma_f32_32x32x16_bf16(av, t1b[kb], accv, 0, 0, 0);
      accg = __builtin_amdgcn_mfma_f32_32x32x16_bf16(ag, t1b[kb], accg, 0, 0, 0);
    }
    barx();
    if (p+2 <= 11) stage_panel<4>(ws + OFF_S2 + (p-6)*16384, buf[p & 1], w, l);
    else           stage_panel<2>(ws + OFF_S3 + (p-10)*8192, buf[p & 1], w, l);
    unsigned W[8];
    #pragma unroll
    for (int q = 0; q < 4; ++q){
      float4 bv = *(const float4*)&blds[256 +       m*32 + 8*q + 4*lh];
      float4 bg = *(const float4*)&blds[256 + 128 + m*32 + 8*q + 4*lh];
      float t0 = (accv[4*q+0] + bv.x) * (1.f/(1.f + __expf(-(accg[4*q+0] + bg.x))));
      float t1 = (accv[4*q+1] + bv.y) * (1.f/(1.f + __expf(-(accg[4*q+1] + bg.y))));
      float t2 = (accv[4*q+2] + bv.z) * (1.f/(1.f + __expf(-(accg[4*q+2] + bg.z))));
      float t3 = (accv[4*q+3] + bv.w) * (1.f/(1.f + __expf(-(accg[4*q+3] + bg.w))));
      W[2*q]   = pk2(t0, t1);
      W[2*q+1] = pk2(t2, t3);
    }
    frags_from_words(W, lh, &tb[2*m], &tb[2*m+1]);
  }

  // ================= stage 3: T @ att_w4 -> z =================
  f32x16 zc[4];
  #pragma unroll
  for (int m = 0; m < 4; ++m){
    const int p = 12 + m;
    f32x16 acc = zero16();
    waitv<2>(); barx();
    const unsigned char* bp = buf[p & 1];
    #pragma unroll
    for (int kb = 0; kb < 8; ++kb){
      short8 a = afrag(bp, cc, kb, lh);
      acc = __builtin_amdgcn_mfma_f32_32x32x16_bf16(a, tb[kb], acc, 0, 0, 0);
    }
    barx();
    if (p+2 <= 15) stage_panel<2>(ws + OFF_S3 + (p-10)*8192, buf[p & 1], w, l);
    else           stage_panel<2>(ws + OFF_S4 + (p-14)*8192, buf[p & 1], w, l);
    #pragma unroll
    for (int q = 0; q < 4; ++q){
      float4 b3 = *(const float4*)&blds[512 + m*32 + 8*q + 4*lh];
      zc[m][4*q+0] = acc[4*q+0] + b3.x;
      zc[m][4*q+1] = acc[4*q+1] + b3.y;
      zc[m][4*q+2] = acc[4*q+2] + b3.z;
      zc[m][4*q+3] = acc[4*q+3] + b3.w;
    }
  }

  // ---- sparsemax per row (row = cc, halves on lanes l and l^32) ----
  float tau, cprev;
  {
    float s = 0.f;
    #pragma unroll
    for (int m = 0; m < 4; ++m)
      #pragma unroll
      for (int i = 0; i < 16; ++i) s += zc[m][i];
    s += sx32f(s);
    tau = (s - 1.f) * (1.f/128.f);
    cprev = 128.f;
  }
  for (int it = 0; it < 32; ++it){
    float s2 = 0.f, c2 = 0.f;
    #pragma unroll
    for (int m = 0; m < 4; ++m)
      #pragma unroll
      for (int i = 0; i < 16; ++i){
        float z = zc[m][i];
        if (z > tau){ s2 += z; c2 += 1.f; }
      }
    s2 += sx32f(s2); c2 += sx32f(c2);
    tau = (s2 - 1.f) / c2;
    int ch = (c2 != cprev);
    cprev = c2;
    if (!__any(ch)) break;
  }

  // ---- P-frags: exchange z to B-layout (f32), multiply with T, pack ----
  short8 pb[8];
  #pragma unroll
  for (int kb = 0; kb < 8; ++kb){
    const int chn = kb >> 1;
    const int ga = (kb & 1) * 2;
    float o[4], sn[4], rv[4];
    #pragma unroll
    for (int i = 0; i < 4; ++i){
      o[i]  = lh ? zc[chn][4*(ga+1) + i] : zc[chn][4*ga + i];
      sn[i] = lh ? zc[chn][4*ga + i]     : zc[chn][4*(ga+1) + i];
    }
    #pragma unroll
    for (int i = 0; i < 4; ++i) rv[i] = sx32f(sn[i]);
    float zB[8];
    #pragma unroll
    for (int i = 0; i < 4; ++i){
      zB[i]   = lh ? rv[i] : o[i];
      zB[4+i] = lh ? o[i]  : rv[i];
    }
    float P[8];
    #pragma unroll
    for (int j = 0; j < 8; ++j){
      float mk = zB[j] - tau;
      mk = mk > 0.f ? mk : 0.f;
      P[j] = bf2f(tb[kb][j]) * mk;
    }
    uint4 u;
    u.x = pk2(P[0], P[1]); u.y = pk2(P[2], P[3]);
    u.z = pk2(P[4], P[5]); u.w = pk2(P[6], P[7]);
    pb[kb] = __builtin_bit_cast(short8, u);
  }

  // ================= stage 4: P @ out_w + b -> out =================
  #pragma unroll
  for (int m = 0; m < 2; ++m){
    const int p = 16 + m;
    f32x16 acc = zero16();
    if (p == 17) waitv<0>(); else waitv<2>();
    barx();
    const unsigned char* bp = buf[p & 1];
    #pragma unroll
    for (int kb = 0; kb < 8; ++kb){
      short8 a = afrag(bp, cc, kb, lh);
      acc = __builtin_amdgcn_mfma_f32_32x32x16_bf16(a, pb[kb], acc, 0, 0, 0);
    }
    #pragma unroll
    for (int q = 0; q < 4; ++q){
      float4 b4 = *(const float4*)&blds[640 + m*32 + 8*q + 4*lh];
      float4 o4;
      o4.x = acc[4*q+0] + b4.x;
      o4.y = acc[4*q+1] + b4.y;
      o4.z = acc[4*q+2] + b4.z;
      o4.w = acc[4*q+3] + b4.w;
      *(float4*)&out[(rowbase + cc)*64 + m*32 + 8*q + 4*lh] = o4;
    }
  }
}

extern "C" void kernel_launch(void* const* d_in, const int* in_sizes, int n_in,
                              void* d_out, int out_size, void* d_ws, size_t ws_size,
                              hipStream_t stream)
{
  const float* feat = (const float*)d_in[0];
  const float* w1  = (const float*)d_in[1];
  const float* b1  = (const float*)d_in[2];
  const float* g1  = (const float*)d_in[3];
  const float* be1 = (const float*)d_in[4];
  const float* w2  = (const float*)d_in[5];
  const float* b2  = (const float*)d_in[6];
  const float* g2  = (const float*)d_in[7];
  const float* be2 = (const float*)d_in[8];
  const float* aw  = (const float*)d_in[9];
  const float* ab  = (const float*)d_in[10];
  const float* ag  = (const float*)d_in[11];
  const float* abe = (const float*)d_in[12];
  const float* ow  = (const float*)d_in[13];
  const float* ob  = (const float*)d_in[14];
  unsigned char* ws = (unsigned char*)d_ws;

  tabnet_prep<<<128, 256, 0, stream>>>(w1,b1,g1,be1, w2,b2,g2,be2, aw,ab,ag,abe, ow,ob, ws);
  tabnet_main<<<2048, 256, 0, stream>>>(feat, ws, (float*)d_out);
}